// Round 4
// baseline (38.680 us; speedup 1.0000x reference)
//
#include <hip/hip_runtime.h>
#include <math.h>

// DMLoss fused kernel for MI355X (gfx950).
// Round 4: register-resident inner loops (readlane broadcast of per-lane
// segment constants -> zero LDS in hot loop), packed fp32 (v_pk_*_f32,
// 2 segments / 2 points per iteration), and final reduction fused into the
// main kernel via an agent-scope atomic ticket (deterministic fixed-order
// reduce by the last block).

#define BB 1024
#define NN 128
#define MM 128

typedef float v2f __attribute__((ext_vector_type(2)));

__device__ __forceinline__ v2f pk_add(v2f a, v2f b) {
    v2f d; asm("v_pk_add_f32 %0, %1, %2" : "=v"(d) : "v"(a), "v"(b)); return d;
}
__device__ __forceinline__ v2f pk_mul(v2f a, v2f b) {
    v2f d; asm("v_pk_mul_f32 %0, %1, %2" : "=v"(d) : "v"(a), "v"(b)); return d;
}
__device__ __forceinline__ v2f pk_fma(v2f a, v2f b, v2f c) {
    v2f d; asm("v_pk_fma_f32 %0, %1, %2, %3" : "=v"(d) : "v"(a), "v"(b), "v"(c)); return d;
}
__device__ __forceinline__ float rdl(float v, int l) {
    return __builtin_bit_cast(float, __builtin_amdgcn_readlane(__builtin_bit_cast(int, v), l));
}
__device__ __forceinline__ float sl1(float x) {
    float d = fabsf(x);
    return d < 1.0f ? 0.5f * d * d : d - 0.5f;
}

__global__ void __launch_bounds__(512, 8)
dmloss_main(const float* __restrict__ ini, const float* __restrict__ pred,
            const float* __restrict__ gt,  const float* __restrict__ kmask,
            float* __restrict__ pA, float* __restrict__ pB, float* __restrict__ pC,
            unsigned* __restrict__ counter, float* __restrict__ out)
{
    const int b    = blockIdx.x;
    const int tid  = threadIdx.x;
    const int n    = tid & 127;     // owned point (pred in B, gt in C)
    const int h    = tid >> 7;      // 0..3: 4-way split of the scan dimension
    const int lane = tid & 63;
    const int u    = lane & 15;     // which segment/point PAIR this lane hosts

    __shared__ float2 s_gt[MM];
    __shared__ float2 s_pr[NN];
    __shared__ float  s_step[16];
    __shared__ float  s_rv[512];
    __shared__ float  s_rf[512];
    __shared__ float  s_sum[3][8];
    __shared__ int    s_last;

    const float2* gt2 = (const float2*)(gt   + (size_t)b * MM * 2);
    const float2* in2 = (const float2*)(ini  + (size_t)b * NN * 2);
    const float2* pr2 = (const float2*)(pred + (size_t)b * NN * 2);

    float2 myPr = make_float2(0.f, 0.f);
    float  myKm = 0.f;
    if (tid < 128) {
        s_gt[tid] = gt2[tid];
        myPr = pr2[tid];
        myKm = kmask[b * MM + tid];
    } else if (tid < 256) {
        s_pr[tid - 128] = pr2[tid - 128];
    } else if (tid < 272) {
        s_step[tid - 256] = (float)(tid - 256) / 10.0f;   // exact j/10
    }

    // Own point + Phase-C lane constants straight from global (no LDS dep).
    const int kA = h + 8 * u;       // pair (kA, kA+4); kA+4 <= 127
    float2 p  = in2[n];
    float2 iA = in2[kA];
    float2 iB = in2[kA + 4];
    const float px = p.x, py = p.y;
    v2f cix = { iA.x, iB.x };
    v2f ciy = { iA.y, iB.y };
    __syncthreads();

    // Phase-B lane constants: segments mA = kA, mB = kA+4.
    // Segment m: a = gt[m-1] -> gt[m]; e = gt[m]-a; jv = ((p-a).e)*10/|e|^2.
    // Stored negated direction so q = a - p works with pk_add:
    //   jv = qx*(-ex*inv) + qy*(-ey*inv);  E = |e|^2/100;
    //   d(jr) = |q|^2 + E*jr*(jr - 2*jv)   (exact convex quadratic in jr)
    v2f cax, cay, cex, cey, cE;
    {
        float2 aA = s_gt[(kA + 127) & 127];
        float2 gA = s_gt[kA];
        float2 aB = s_gt[kA + 3];
        float2 gB = s_gt[kA + 4];
        float exA = gA.x - aA.x, eyA = gA.y - aA.y;
        float exB = gB.x - aB.x, eyB = gB.y - aB.y;
        float AA = exA * exA + eyA * eyA;
        float AB = exB * exB + eyB * eyB;
        float invA = AA > 0.f ? 10.f / AA : 0.f;   // degenerate seg -> jv = 0
        float invB = AB > 0.f ? 10.f / AB : 0.f;
        cax = (v2f){ aA.x, aB.x };
        cay = (v2f){ aA.y, aB.y };
        cex = (v2f){ -exA * invA, -exB * invB };
        cey = (v2f){ -eyA * invA, -eyB * invB };
        cE  = (v2f){ AA * 0.01f, AB * 0.01f };
    }

    const v2f pxn = { -px, -px };
    const v2f pyn = { -py, -py };
    const v2f m2  = { -2.f, -2.f };
    float sumA = 0.f, sumB = 0.f, sumC = 0.f;

    // ---- Phase B: per pred point, argmin over 1280 interp points ----
    // Two interleaved chains (even/odd pair halves); indices ascend with t in
    // each chain, so strict < keeps first occurrence.
    float dE = INFINITY, dO = INFINITY;
    float cdE = 0.f, cdO = 0.f, jrE = 0.f, jrO = 0.f;
    #pragma unroll
    for (int t = 0; t < 16; ++t) {
        v2f ax, ay, ex, ey, E;
        ax.x = rdl(cax.x, t); ax.y = rdl(cax.y, t);
        ay.x = rdl(cay.x, t); ay.y = rdl(cay.y, t);
        ex.x = rdl(cex.x, t); ex.y = rdl(cex.y, t);
        ey.x = rdl(cey.x, t); ey.y = rdl(cey.y, t);
        E.x  = rdl(cE.x,  t); E.y  = rdl(cE.y,  t);
        v2f qx = pk_add(ax, pxn);                     // a - p (x)
        v2f qy = pk_add(ay, pyn);                     // a - p (y)
        v2f jv = pk_fma(qy, ey, pk_mul(qx, ex));      // vertex (j units), sign-folded
        v2f jr;
        jr.x = rintf(fminf(fmaxf(jv.x, 0.f), 9.f));
        jr.y = rintf(fminf(fmaxf(jv.y, 0.f), 9.f));
        v2f q2 = pk_fma(qy, qy, pk_mul(qx, qx));      // |p-a|^2
        v2f t2 = pk_fma(jv, m2, jr);                  // jr - 2*jv
        v2f d2 = pk_fma(pk_mul(E, jr), t2, q2);
        if (d2.x < dE) { dE = d2.x; cdE = (float)t; jrE = jr.x; }
        if (d2.y < dO) { dO = d2.y; cdO = (float)t; jrO = jr.y; }
    }
    {
        // decode: even chain m = h+8t -> i = 10h + 80t + jr ; odd: +40
        float hb  = (float)(10 * h);
        float fiE = fmaf(80.f, cdE, hb + jrE);
        float fiO = fmaf(80.f, cdO, hb + 40.f + jrO);
        float best = dE, bf = fiE;
        if (dO < best || (dO == best && fiO < bf)) { best = dO; bf = fiO; }
        s_rv[tid] = best; s_rf[tid] = bf;
    }
    __syncthreads();
    if (h == 0) {
        float best = s_rv[tid], bf = s_rf[tid];
        #pragma unroll
        for (int q = 1; q < 4; ++q) {
            float ov = s_rv[n + 128 * q];
            float of = s_rf[n + 128 * q];
            if (ov < best || (ov == best && of < bf)) { best = ov; bf = of; }
        }
        int bidx = (int)bf;
        int m = bidx / 10;
        int j = bidx - m * 10;
        float s = s_step[j];
        float tt = 1.0f - s;
        float2 gm = s_gt[m];
        float2 gp = s_gt[(m + 127) & 127];
        float gx = gm.x * s + gp.x * tt;   // exact reference interp formula
        float gy = gm.y * s + gp.y * tt;
        sumA = sl1(myPr.x - gx) + sl1(myPr.y - gy);
    }
    __syncthreads();   // protect s_rv/s_rf reuse

    // ---- Phase C: per gt point, argmin over 128 ini_pred points ----
    {
        float2 g = s_gt[n];
        const v2f gxn = { -g.x, -g.x };
        const v2f gyn = { -g.y, -g.y };
        float d2E = INFINITY, d2O = INFINITY;
        float c2E = 0.f, c2O = 0.f;
        #pragma unroll
        for (int t = 0; t < 16; ++t) {
            v2f ix, iy;
            ix.x = rdl(cix.x, t); ix.y = rdl(cix.y, t);
            iy.x = rdl(ciy.x, t); iy.y = rdl(ciy.y, t);
            v2f dx = pk_add(ix, gxn);
            v2f dy = pk_add(iy, gyn);
            v2f d2 = pk_fma(dy, dy, pk_mul(dx, dx));
            if (d2.x < d2E) { d2E = d2.x; c2E = (float)t; }
            if (d2.y < d2O) { d2O = d2.y; c2O = (float)t; }
        }
        float hf = (float)h;
        float fE = fmaf(8.f, c2E, hf);          // k = h + 8t
        float fO = fmaf(8.f, c2O, hf + 4.f);    // k = h + 8t + 4
        float best = d2E, bf = fE;
        if (d2O < best || (d2O == best && fO < bf)) { best = d2O; bf = fO; }
        s_rv[tid] = best; s_rf[tid] = bf;
        __syncthreads();
        if (h == 0) {
            float2 g0 = s_gt[tid];
            float bst = s_rv[tid], bfi = s_rf[tid];
            #pragma unroll
            for (int q = 1; q < 4; ++q) {
                float ov = s_rv[n + 128 * q];
                float of = s_rf[n + 128 * q];
                if (ov < bst || (ov == bst && of < bfi)) { bst = ov; bfi = of; }
            }
            int k = (int)bfi;
            float2 pk2 = s_pr[k];
            sumB = myKm * (sl1(pk2.x - g0.x) + sl1(pk2.y - g0.y));
            sumC = myKm;
        }
    }

    // ---- Block reduction of (sumA, sumB, sumC) ----
    #pragma unroll
    for (int off = 32; off > 0; off >>= 1) {
        sumA += __shfl_down(sumA, off);
        sumB += __shfl_down(sumB, off);
        sumC += __shfl_down(sumC, off);
    }
    const int wave = tid >> 6;
    if ((tid & 63) == 0) {
        s_sum[0][wave] = sumA; s_sum[1][wave] = sumB; s_sum[2][wave] = sumC;
    }
    __syncthreads();
    if (tid == 0) {
        float A = 0.f, Bs = 0.f, C = 0.f;
        #pragma unroll
        for (int w = 0; w < 8; ++w) {
            A += s_sum[0][w]; Bs += s_sum[1][w]; C += s_sum[2][w];
        }
        __hip_atomic_store(&pA[b], A,  __ATOMIC_RELAXED, __HIP_MEMORY_SCOPE_AGENT);
        __hip_atomic_store(&pB[b], Bs, __ATOMIC_RELAXED, __HIP_MEMORY_SCOPE_AGENT);
        __hip_atomic_store(&pC[b], C,  __ATOMIC_RELAXED, __HIP_MEMORY_SCOPE_AGENT);
        unsigned prev = __hip_atomic_fetch_add(counter, 1u, __ATOMIC_ACQ_REL,
                                               __HIP_MEMORY_SCOPE_AGENT);
        s_last = (prev == (unsigned)(BB - 1));
    }
    __syncthreads();

    // ---- Fused final reduction: exactly one block, fixed tid order ----
    if (s_last) {
        float A = 0.f, Bs = 0.f, C = 0.f;
        #pragma unroll
        for (int i = tid; i < BB; i += 512) {
            A  += __hip_atomic_load(&pA[i], __ATOMIC_RELAXED, __HIP_MEMORY_SCOPE_AGENT);
            Bs += __hip_atomic_load(&pB[i], __ATOMIC_RELAXED, __HIP_MEMORY_SCOPE_AGENT);
            C  += __hip_atomic_load(&pC[i], __ATOMIC_RELAXED, __HIP_MEMORY_SCOPE_AGENT);
        }
        #pragma unroll
        for (int off = 32; off > 0; off >>= 1) {
            A  += __shfl_down(A, off);
            Bs += __shfl_down(Bs, off);
            C  += __shfl_down(C, off);
        }
        if ((tid & 63) == 0) {
            s_sum[0][wave] = A; s_sum[1][wave] = Bs; s_sum[2][wave] = C;
        }
        __syncthreads();
        if (tid == 0) {
            float a = 0.f, bs = 0.f, c = 0.f;
            #pragma unroll
            for (int w = 0; w < 8; ++w) {
                a += s_sum[0][w]; bs += s_sum[1][w]; c += s_sum[2][w];
            }
            float loss_pred2gt = a / ((float)BB * (float)NN * 2.0f);
            float loss_set2set = bs / (2.0f * c + 1.0f) + loss_pred2gt;
            out[0] = 0.5f * loss_set2set;
        }
    }
}

extern "C" void kernel_launch(void* const* d_in, const int* in_sizes, int n_in,
                              void* d_out, int out_size, void* d_ws, size_t ws_size,
                              hipStream_t stream)
{
    const float* ini   = (const float*)d_in[0];
    const float* pred  = (const float*)d_in[1];
    const float* gt    = (const float*)d_in[2];
    const float* kmask = (const float*)d_in[3];

    float*    pA      = (float*)d_ws;                 // [1024]
    float*    pB      = pA + BB;                      // [1024]
    float*    pC      = pB + BB;                      // [1024]
    unsigned* counter = (unsigned*)(pC + BB);         // [1]

    hipMemsetAsync(counter, 0, sizeof(unsigned), stream);
    dmloss_main<<<dim3(BB), dim3(512), 0, stream>>>(ini, pred, gt, kmask,
                                                    pA, pB, pC, counter,
                                                    (float*)d_out);
}

// Round 5
// 32.072 us; speedup vs baseline: 1.2060x; 1.2060x over previous
//
#include <hip/hip_runtime.h>
#include <math.h>

// DMLoss fused kernels for MI355X (gfx950).
// Round 5: hot-loop constants moved to the SCALAR pipe. A prep kernel builds a
// per-batch segment table (SoA, 6x128 floats) in global scratch; the main
// kernel reads it through wave-uniform addresses -> s_load into SGPRs, so the
// inner loops issue ~16 VALU per segment with ZERO LDS traffic (R3 was
// LDS-pipe bound: 96 ds_read_b128/wave ~= 15us/CU). Phase C scans ini points
// via uniform scalar loads directly from the input. Final reduction fused via
// atomic ticket (R4 pattern, verified).

#define BB 1024
#define NN 128
#define MM 128
#define SEG_STRIDE 768   // 6 arrays * 128 floats per batch

__device__ __forceinline__ float sl1(float x) {
    float d = fabsf(x);
    return d < 1.0f ? 0.5f * d * d : d - 0.5f;
}

// ---------------- prep: per-batch segment tables + counter zero ----------------
__global__ void __launch_bounds__(128)
dmloss_prep(const float* __restrict__ gt, float* __restrict__ seg,
            unsigned* __restrict__ counter)
{
    const int b = blockIdx.x;
    const int m = threadIdx.x;
    if (b == 0 && m == 0) *counter = 0u;

    __shared__ float2 sg[MM];
    const float2* g2 = (const float2*)(gt + (size_t)b * MM * 2);
    sg[m] = g2[m];
    __syncthreads();

    float2 g = sg[m];
    float2 a = sg[(m + 127) & 127];
    float ex = g.x - a.x, ey = g.y - a.y;
    float A  = ex * ex + ey * ey;
    float inv = A > 0.f ? 10.f / A : 0.f;   // degenerate segment -> vertex 0

    float* tb = seg + (size_t)b * SEG_STRIDE;
    tb[m]       = a.x;          // A1
    tb[128 + m] = a.y;          // A2
    tb[256 + m] = ex * inv;     // X  (jv = -(q.X, q.Y) with q = a - p)
    tb[384 + m] = ey * inv;     // Y
    tb[512 + m] = ex * 0.1f;    // U  (e/10)
    tb[640 + m] = ey * 0.1f;    // V
}

// ---------------- main ----------------
__global__ void __launch_bounds__(512, 8)
dmloss_main(const float* __restrict__ ini, const float* __restrict__ pred,
            const float* __restrict__ gt,  const float* __restrict__ kmask,
            const float* __restrict__ seg,
            float* __restrict__ pA, float* __restrict__ pB, float* __restrict__ pC,
            unsigned* __restrict__ counter, float* __restrict__ out)
{
    const int b   = blockIdx.x;
    const int tid = threadIdx.x;
    const int n   = tid & 127;   // owned point (pred in B, gt in C)
    const int h   = tid >> 7;    // 0..3: contiguous 32-wide slice of the scan dim

    __shared__ float2 s_gt[MM];
    __shared__ float2 s_pr[NN];
    __shared__ float  s_step[16];
    __shared__ float  s_rv[512];
    __shared__ float  s_rf[512];
    __shared__ float  s_sum[3][8];
    __shared__ int    s_last;

    const float2* gt2 = (const float2*)(gt   + (size_t)b * MM * 2);
    const float2* in2 = (const float2*)(ini  + (size_t)b * NN * 2);
    const float2* pr2 = (const float2*)(pred + (size_t)b * NN * 2);

    float2 myPr = make_float2(0.f, 0.f);
    float  myKm = 0.f;
    if (tid < 128) {
        s_gt[tid] = gt2[tid];
        myPr = pr2[tid];
        myKm = kmask[b * MM + tid];
    } else if (tid < 256) {
        s_pr[tid - 128] = pr2[tid - 128];
    } else if (tid < 272) {
        s_step[tid - 256] = (float)(tid - 256) / 10.0f;   // exact j/10
    }

    float2 p = in2[n];
    const float px = p.x, py = p.y;

    // Wave-uniform scalar base offsets (readfirstlane forces SGPR).
    const int hs   = __builtin_amdgcn_readfirstlane(h);
    const float* tb = seg + (size_t)b * SEG_STRIDE + 32 * hs;   // + {0,128,..,640}[arr]

    float sumA = 0.f, sumB = 0.f, sumC = 0.f;

    // ---- Phase B: per pred point, argmin over 1280 interp points ----
    // Segment slice [32h, 32h+32). Constants land in SGPRs (s_load); each VALU
    // op reads at most one SGPR. d(jr) = |q + e10*jr|^2, q = a - p;
    // vertex jv = -(qx*X + qy*Y); candidate jr = rint(clamp(jv, 0, 9)).
    float best = INFINITY, bf = 1e30f;
    {
        const float fbase = (float)(320 * hs);   // 10 * 32h
        #pragma unroll
        for (int i = 0; i < 32; ++i) {
            float ax = tb[i], ay = tb[128 + i];
            float X  = tb[256 + i], Y = tb[384 + i];
            float U  = tb[512 + i], V = tb[640 + i];
            float qx = ax - px, qy = ay - py;
            float w  = fmaf(qy, Y, qx * X);            // = -jv
            float jc = fminf(fmaxf(-w, 0.f), 9.f);
            float jr = rintf(jc);
            float gxq = fmaf(jr, U, qx);
            float gyq = fmaf(jr, V, qy);
            float d  = fmaf(gyq, gyq, gxq * gxq);
            float fi = fbase + (float)(10 * i) + jr;   // absolute interp index
            if (d < best) { best = d; bf = fi; }       // ascending -> first occ.
        }
    }
    __syncthreads();           // staging (s_gt/s_pr/s_step) complete, rv/rf free
    s_rv[tid] = best; s_rf[tid] = bf;
    __syncthreads();
    if (h == 0) {
        #pragma unroll
        for (int q = 1; q < 4; ++q) {
            float ov = s_rv[n + 128 * q];
            float of = s_rf[n + 128 * q];
            if (ov < best || (ov == best && of < bf)) { best = ov; bf = of; }
        }
        int bidx = (int)bf;
        int m = bidx / 10;
        int j = bidx - m * 10;
        float s  = s_step[j];
        float tt = 1.0f - s;
        float2 gm = s_gt[m];
        float2 gp = s_gt[(m + 127) & 127];
        float gx = gm.x * s + gp.x * tt;   // exact reference interp formula
        float gy = gm.y * s + gp.y * tt;
        sumA = sl1(myPr.x - gx) + sl1(myPr.y - gy);
    }
    __syncthreads();           // protect s_rv/s_rf reuse

    // ---- Phase C: per gt point, argmin over 128 ini_pred points ----
    {
        float2 g = s_gt[n];
        const float gx = g.x, gy = g.y;
        // Uniform slice of the ini block: points [32h, 32h+32) -> scalar loads.
        const int ioff = __builtin_amdgcn_readfirstlane(b * (NN * 2) + 64 * h);
        const float* ti = ini + ioff;
        const float fb2 = (float)(32 * hs);
        best = INFINITY; bf = 1e30f;
        #pragma unroll
        for (int j = 0; j < 32; ++j) {
            float dx = ti[2 * j]     - gx;
            float dy = ti[2 * j + 1] - gy;
            float d  = fmaf(dy, dy, dx * dx);
            float fi = fb2 + (float)j;
            if (d < best) { best = d; bf = fi; }
        }
        s_rv[tid] = best; s_rf[tid] = bf;
        __syncthreads();
        if (h == 0) {
            #pragma unroll
            for (int q = 1; q < 4; ++q) {
                float ov = s_rv[n + 128 * q];
                float of = s_rf[n + 128 * q];
                if (ov < best || (ov == best && of < bf)) { best = ov; bf = of; }
            }
            int k = (int)bf;
            float2 pk2 = s_pr[k];
            sumB = myKm * (sl1(pk2.x - gx) + sl1(pk2.y - gy));
            sumC = myKm;
        }
    }

    // ---- Block reduction of (sumA, sumB, sumC) ----
    #pragma unroll
    for (int off = 32; off > 0; off >>= 1) {
        sumA += __shfl_down(sumA, off);
        sumB += __shfl_down(sumB, off);
        sumC += __shfl_down(sumC, off);
    }
    const int wave = tid >> 6;
    if ((tid & 63) == 0) {
        s_sum[0][wave] = sumA; s_sum[1][wave] = sumB; s_sum[2][wave] = sumC;
    }
    __syncthreads();
    if (tid == 0) {
        float A = 0.f, Bs = 0.f, C = 0.f;
        #pragma unroll
        for (int w = 0; w < 8; ++w) {
            A += s_sum[0][w]; Bs += s_sum[1][w]; C += s_sum[2][w];
        }
        __hip_atomic_store(&pA[b], A,  __ATOMIC_RELAXED, __HIP_MEMORY_SCOPE_AGENT);
        __hip_atomic_store(&pB[b], Bs, __ATOMIC_RELAXED, __HIP_MEMORY_SCOPE_AGENT);
        __hip_atomic_store(&pC[b], C,  __ATOMIC_RELAXED, __HIP_MEMORY_SCOPE_AGENT);
        unsigned prev = __hip_atomic_fetch_add(counter, 1u, __ATOMIC_ACQ_REL,
                                               __HIP_MEMORY_SCOPE_AGENT);
        s_last = (prev == (unsigned)(BB - 1));
    }
    __syncthreads();

    // ---- Fused final reduction: exactly one block, fixed tid order ----
    if (s_last) {
        float A = 0.f, Bs = 0.f, C = 0.f;
        #pragma unroll
        for (int i = tid; i < BB; i += 512) {
            A  += __hip_atomic_load(&pA[i], __ATOMIC_RELAXED, __HIP_MEMORY_SCOPE_AGENT);
            Bs += __hip_atomic_load(&pB[i], __ATOMIC_RELAXED, __HIP_MEMORY_SCOPE_AGENT);
            C  += __hip_atomic_load(&pC[i], __ATOMIC_RELAXED, __HIP_MEMORY_SCOPE_AGENT);
        }
        #pragma unroll
        for (int off = 32; off > 0; off >>= 1) {
            A  += __shfl_down(A, off);
            Bs += __shfl_down(Bs, off);
            C  += __shfl_down(C, off);
        }
        if ((tid & 63) == 0) {
            s_sum[0][wave] = A; s_sum[1][wave] = Bs; s_sum[2][wave] = C;
        }
        __syncthreads();
        if (tid == 0) {
            float a = 0.f, bs = 0.f, c = 0.f;
            #pragma unroll
            for (int w = 0; w < 8; ++w) {
                a += s_sum[0][w]; bs += s_sum[1][w]; c += s_sum[2][w];
            }
            float loss_pred2gt = a / ((float)BB * (float)NN * 2.0f);
            float loss_set2set = bs / (2.0f * c + 1.0f) + loss_pred2gt;
            out[0] = 0.5f * loss_set2set;
        }
    }
}

extern "C" void kernel_launch(void* const* d_in, const int* in_sizes, int n_in,
                              void* d_out, int out_size, void* d_ws, size_t ws_size,
                              hipStream_t stream)
{
    const float* ini   = (const float*)d_in[0];
    const float* pred  = (const float*)d_in[1];
    const float* gt    = (const float*)d_in[2];
    const float* kmask = (const float*)d_in[3];

    float*    seg     = (float*)d_ws;                      // 1024*768 floats = 3 MB
    float*    pA      = seg + (size_t)BB * SEG_STRIDE;     // [1024]
    float*    pB      = pA + BB;
    float*    pC      = pB + BB;
    unsigned* counter = (unsigned*)(pC + BB);

    dmloss_prep<<<dim3(BB), dim3(128), 0, stream>>>(gt, seg, counter);
    dmloss_main<<<dim3(BB), dim3(512), 0, stream>>>(ini, pred, gt, kmask, seg,
                                                    pA, pB, pC, counter,
                                                    (float*)d_out);
}